// Round 6
// baseline (7568.162 us; speedup 1.0000x reference)
//
#include <hip/hip_runtime.h>
#include <hip/hip_bf16.h>

#define F_IN  256
#define UNITS 512
#define T_SEQ 1024
#define B_SZ  32
#define NCLS  50
#define NG    16    // workgroups per direction
#define NWAVE 6     // waves per workgroup
#define SCOPE __HIP_MEMORY_SCOPE_AGENT

typedef short s16x8 __attribute__((ext_vector_type(8)));
typedef float f32x16 __attribute__((ext_vector_type(16)));

__device__ __forceinline__ ushort f2bf(float f) {
  union { float f; unsigned u; } v; v.f = f;
  unsigned r = v.u + 0x7fffu + ((v.u >> 16) & 1u);   // round-to-nearest-even
  return (ushort)(r >> 16);
}

// ---------------- prep kernels ----------------

// x [32][1024][256] f32  ->  xT [1024][32][256] bf16
__global__ void prep_xT(const float* __restrict__ x, ushort* __restrict__ xT) {
  int idx = blockIdx.x * 256 + threadIdx.x;      // chunk of 8 over [32][1024][32]
  int b = idx >> 15;
  int r = idx & 32767;
  int t = r >> 5;
  int c = r & 31;
  const float4* s4 = (const float4*)(x + ((size_t)b * T_SEQ + t) * F_IN + c * 8);
  float4 f0 = s4[0], f1 = s4[1];
  s16x8 o;
  o[0] = (short)f2bf(f0.x); o[1] = (short)f2bf(f0.y);
  o[2] = (short)f2bf(f0.z); o[3] = (short)f2bf(f0.w);
  o[4] = (short)f2bf(f1.x); o[5] = (short)f2bf(f1.y);
  o[6] = (short)f2bf(f1.z); o[7] = (short)f2bf(f1.w);
  *(s16x8*)(xT + ((size_t)t * B_SZ + b) * F_IN + c * 8) = o;
}

// UWT[d][n][k] bf16, n in [0,1536), k in [0,768): k<512 -> U_d[k][n], k>=512 -> W_d[k-512][n]
__global__ void prep_UWT(const float* __restrict__ Uf, const float* __restrict__ Wf,
                         const float* __restrict__ Ub, const float* __restrict__ Wb,
                         ushort* __restrict__ UWT) {
  int idx = blockIdx.x * 256 + threadIdx.x;      // chunk of 8 over [2][1536][96]
  int d = idx / 147456;
  int r = idx % 147456;
  int n = r / 96;
  int ck = r % 96;
  const float* U = d ? Ub : Uf;
  const float* W = d ? Wb : Wf;
  s16x8 o;
  #pragma unroll
  for (int i = 0; i < 8; ++i) {
    int k = ck * 8 + i;
    float v = (k < UNITS) ? U[(size_t)k * 1536 + n] : W[(size_t)(k - UNITS) * 1536 + n];
    o[i] = (short)f2bf(v);
  }
  *(s16x8*)(UWT + ((size_t)d * 1536 + n) * 768 + ck * 8) = o;
}

// WdT [64][1024] bf16 (rows 50..63 zero) from Wd [1024][50]
__global__ void prep_WdT(const float* __restrict__ Wd, ushort* __restrict__ WdT) {
  int idx = blockIdx.x * 256 + threadIdx.x;      // 65536
  int n = idx >> 10, k = idx & 1023;
  float v = (n < NCLS) ? Wd[(size_t)k * NCLS + n] : 0.f;
  WdT[idx] = f2bf(v);
}

// ---------------- persistent bidirectional GRU recurrence ----------------
// 512 WGs launched (= 2/CU residency bound, all co-resident). Each WG reads
// HW_REG_XCC_ID (m09-verified); WGs on XCD0 claim the 16 forward slots, XCD1
// the 16 backward slots (device atomic); the other ~480 exit. All 16 WGs of
// a direction share ONE XCD, so each h line is pulled from L3 into exactly
// one L2 (first toucher ~900cy, the rest L2-hit ~250cy) and xT/UWT stay
// L2-resident. Memory protocol is UNCHANGED from R5 (all primitives proven):
//   producer: gate math -> agent-scope bf16 stores -> __syncthreads (vmcnt
//             drain at coherence point) -> ONE agent tag word per WG (s+1).
//   consumer: wave 0 polls the 16 WG-tags (agent loads, s_sleep backoff);
//             __syncthreads releases; plain cached payload loads -> MFMA.
// Plain consumer loads are safe: each h address is written once per dispatch
// before any read (fresh t-slot per step), dispatch starts caches-invalid.
// Claim nondeterminism only permutes WG<->slot assignment -> output exact.
__global__ __launch_bounds__(384, 2) void gru_rec(
    const ushort* __restrict__ xT,      // [1024][32][256] bf16
    const ushort* __restrict__ UWT,     // [2][1536][768] bf16
    const float* __restrict__ bias_f,   // [2][1536] f32
    const float* __restrict__ bias_b,
    ushort* __restrict__ h_out,         // [2][1024][32][512] bf16
    unsigned* __restrict__ tags,        // [2][16] monotone step counters
    unsigned* __restrict__ claim)       // [2] slot claim counters
{
  const int tid  = threadIdx.x;

  unsigned xcc;
  asm volatile("s_getreg_b32 %0, hwreg(HW_REG_XCC_ID)" : "=s"(xcc));

  __shared__ int s_slot;
  if (tid == 0) {
    int sl = -1;
    if (xcc <= 1) {
      unsigned t = __hip_atomic_fetch_add(&claim[xcc], 1u, __ATOMIC_RELAXED, SCOPE);
      if (t < NG) sl = (int)(xcc * NG + t);
    }
    s_slot = sl;
  }
  __syncthreads();
  if (s_slot < 0) return;
  const int d  = s_slot >> 4;    // direction == XCD id
  const int gg = s_slot & 15;

  const int wv   = tid >> 6;
  const int lane = tid & 63;
  const int col  = lane & 31;
  const int half = lane >> 5;
  const int gate = wv >> 1;
  const int kh   = wv & 1;

  __shared__ float slot[2][32][128];  // [kh][row][ z(0:32) r(32:64) rh(64:96) xh(96:128) ]

  // --- B-fragment preload: 24 chunks of K=16 (96 VGPRs) ---
  s16x8 bfrag[24];
  {
    const ushort* bp = UWT + ((size_t)d * 1536 + gate * UNITS + gg * 32 + col) * 768
                       + kh * 384 + half * 8;
    #pragma unroll
    for (int c = 0; c < 24; ++c) bfrag[c] = *(const s16x8*)(bp + c * 16);
  }

  // --- per-thread gate biases and persistent h state (3 elems/thread) ---
  const float* bias = d ? bias_b : bias_f;
  float bz[3], br[3], bih[3], brh[3], hprev[3];
  #pragma unroll
  for (int i = 0; i < 3; ++i) {
    int e = tid + 384 * i;
    int j = gg * 32 + (e & 31);
    bz[i] = br[i] = bih[i] = brh[i] = 0.f;
    hprev[i] = 0.f;
    if (e < 1024) {
      bz[i]  = bias[j]        + bias[1536 + j];
      br[i]  = bias[512 + j]  + bias[1536 + 512 + j];
      bih[i] = bias[1024 + j];
      brh[i] = bias[1536 + 1024 + j];
    }
  }

  for (int s = 0; s < T_SEQ; ++s) {
    const int t_in = d ? (T_SEQ - 1 - s) : s;
    // dual accumulators break the serial MFMA dependency chain
    f32x16 acc_a, acc_a2, acc_b, acc_b2;
    #pragma unroll
    for (int i = 0; i < 16; ++i) { acc_a[i] = 0.f; acc_a2[i] = 0.f; acc_b[i] = 0.f; acc_b2[i] = 0.f; }

    // input projection (kh==1 waves own K[512:768) = x). Wave 0 (kh=0) has no
    // x-work: it proceeds straight to the poll.
    if (kh) {
      const ushort* xp = xT + ((size_t)t_in * B_SZ + col) * F_IN + half * 8;
      s16x8 a[16];
      #pragma unroll
      for (int i = 0; i < 16; ++i) a[i] = *(const s16x8*)(xp + i * 16);
      #pragma unroll
      for (int i = 0; i < 8; ++i) {
        acc_b  = __builtin_amdgcn_mfma_f32_32x32x16_bf16(a[2*i],   bfrag[8 + 2*i],   acc_b,  0, 0, 0);
        acc_b2 = __builtin_amdgcn_mfma_f32_32x32x16_bf16(a[2*i+1], bfrag[8 + 2*i+1], acc_b2, 0, 0, 0);
      }
    }

    if (s > 0) {
      if (wv == 0) {
        const unsigned expv = (unsigned)s;
        const unsigned* tg = tags + d * NG;
        bool done;
        do {
          unsigned v = (lane < NG)
              ? __hip_atomic_load(tg + lane, __ATOMIC_RELAXED, SCOPE) : expv;
          done = __all(v >= expv);
          if (!done) __builtin_amdgcn_s_sleep(1);
        } while (!done);
      }
      __syncthreads();   // B1: release all waves; full fence for payload loads

      const int t_prev = d ? (T_SEQ - s) : (s - 1);
      const ushort* ap = h_out + ((size_t)(d * T_SEQ + t_prev) * B_SZ + col) * UNITS
                         + kh * 384 + half * 8;
      if (kh) {               // h[384:512): 8 fragments, interleaved on 2 accs
        s16x8 a[8];
        #pragma unroll
        for (int i = 0; i < 8; ++i) a[i] = *(const s16x8*)(ap + i * 16);
        #pragma unroll
        for (int i = 0; i < 4; ++i) {
          acc_a  = __builtin_amdgcn_mfma_f32_32x32x16_bf16(a[2*i],   bfrag[2*i],   acc_a,  0, 0, 0);
          acc_a2 = __builtin_amdgcn_mfma_f32_32x32x16_bf16(a[2*i+1], bfrag[2*i+1], acc_a2, 0, 0, 0);
        }
      } else {                // h[0:384): 24 fragments, 2 batches of 12, 2 accs
        #pragma unroll
        for (int grp = 0; grp < 2; ++grp) {
          s16x8 a[12];
          #pragma unroll
          for (int i = 0; i < 12; ++i) a[i] = *(const s16x8*)(ap + (grp * 12 + i) * 16);
          #pragma unroll
          for (int i = 0; i < 6; ++i) {
            acc_a  = __builtin_amdgcn_mfma_f32_32x32x16_bf16(a[2*i],   bfrag[grp*12 + 2*i],   acc_a,  0, 0, 0);
            acc_a2 = __builtin_amdgcn_mfma_f32_32x32x16_bf16(a[2*i+1], bfrag[grp*12 + 2*i+1], acc_a2, 0, 0, 0);
          }
        }
      }
    }

    // C/D layout: col = lane&31, row = (reg&3) + 8*(reg>>2) + 4*(lane>>5)
    #pragma unroll
    for (int i = 0; i < 16; ++i) {
      int brow = (i & 3) + 8 * (i >> 2) + 4 * half;
      float ra = acc_a[i] + acc_a2[i];
      float rb = acc_b[i] + acc_b2[i];
      if (gate < 2) {
        slot[kh][brow][gate * 32 + col] = ra + rb;
      } else {
        slot[kh][brow][64 + col] = ra;               // recurrent h-gate partial
        if (kh) slot[1][brow][96 + col] = rb;        // input h-gate part
      }
    }
    __syncthreads();   // B2: slot complete

    // gate math + publish h_new (agent-scope write-through stores)
    #pragma unroll
    for (int i = 0; i < 3; ++i) {
      int e = tid + 384 * i;
      if (e < 1024) {
        int b = e >> 5, j = e & 31;
        float rz = slot[0][b][j]      + slot[1][b][j]      + bz[i];
        float rr = slot[0][b][32 + j] + slot[1][b][32 + j] + br[i];
        float rh = slot[0][b][64 + j] + slot[1][b][64 + j] + brh[i];
        float xh = slot[1][b][96 + j] + bih[i];
        rz = fminf(fmaxf(rz, -30.f), 30.f);
        rr = fminf(fmaxf(rr, -30.f), 30.f);
        float z  = 1.f / (1.f + __expf(-rz));
        float rg = 1.f / (1.f + __expf(-rr));
        float ti = xh + rg * rh;
        ti = fminf(fmaxf(ti, -15.f), 15.f);
        float ex = __expf(2.f * ti);
        float hh = (ex - 1.f) / (ex + 1.f);
        float hn = z * hprev[i] + (1.f - z) * hh;
        hprev[i] = hn;
        __hip_atomic_store(
            h_out + ((size_t)(d * T_SEQ + t_in) * B_SZ + b) * UNITS + gg * 32 + j,
            (ushort)f2bf(hn), __ATOMIC_RELAXED, SCOPE);
      }
    }
    // B3: __syncthreads drains vmcnt(0) in every wave -> all 6 waves' payload
    // stores are at the coherence point; then ONE tag store per WG.
    __syncthreads();
    if (tid == 0)
      __hip_atomic_store(tags + d * NG + gg, (unsigned)(s + 1),
                         __ATOMIC_RELAXED, SCOPE);
  }
}

// ---------------- dense + softmax ----------------
__global__ __launch_bounds__(256) void dense_softmax(
    const ushort* __restrict__ h_out,   // [2][1024][32][512] bf16
    const ushort* __restrict__ WdT,     // [64][1024] bf16
    const float* __restrict__ bd,       // [50]
    float* __restrict__ out)            // [32][1024][50] f32
{
  const int tid  = threadIdx.x;
  const int w    = tid >> 6, lane = tid & 63;
  const int col  = lane & 31, half = lane >> 5;
  const int t = blockIdx.x * 4 + w;

  __shared__ float lds[4][32][66];

  f32x16 acc0, acc1;
  #pragma unroll
  for (int i = 0; i < 16; ++i) { acc0[i] = 0.f; acc1[i] = 0.f; }

  const ushort* af  = h_out + ((size_t)t * B_SZ + col) * UNITS + half * 8;
  const ushort* ab  = h_out + ((size_t)(T_SEQ + t) * B_SZ + col) * UNITS + half * 8;
  const ushort* bp0 = WdT + (size_t)col * 1024 + half * 8;
  const ushort* bp1 = WdT + (size_t)(col + 32) * 1024 + half * 8;

  #pragma unroll 4
  for (int ks = 0; ks < 64; ++ks) {
    s16x8 a  = (ks < 32) ? *(const s16x8*)(af + ks * 16)
                         : *(const s16x8*)(ab + (ks - 32) * 16);
    s16x8 b0 = *(const s16x8*)(bp0 + ks * 16);
    s16x8 b1 = *(const s16x8*)(bp1 + ks * 16);
    acc0 = __builtin_amdgcn_mfma_f32_32x32x16_bf16(a, b0, acc0, 0, 0, 0);
    acc1 = __builtin_amdgcn_mfma_f32_32x32x16_bf16(a, b1, acc1, 0, 0, 0);
  }

  #pragma unroll
  for (int i = 0; i < 16; ++i) {
    int b = (i & 3) + 8 * (i >> 2) + 4 * half;
    lds[w][b][col]      = acc0[i];
    lds[w][b][32 + col] = acc1[i];
  }
  __syncthreads();

  if (tid < 128) {
    int tl = tid >> 5, b = tid & 31;
    int tt = blockIdx.x * 4 + tl;
    float v[NCLS];
    float m = -1e30f;
    #pragma unroll
    for (int c = 0; c < NCLS; ++c) { v[c] = lds[tl][b][c] + bd[c]; m = fmaxf(m, v[c]); }
    float sum = 0.f;
    #pragma unroll
    for (int c = 0; c < NCLS; ++c) { float e = __expf(v[c] - m); v[c] = e; sum += e; }
    float inv = 1.f / sum;
    float* op = out + ((size_t)b * T_SEQ + tt) * NCLS;
    #pragma unroll
    for (int c = 0; c < NCLS; ++c) op[c] = v[c] * inv;
  }
}

// ---------------- launch ----------------
extern "C" void kernel_launch(void* const* d_in, const int* in_sizes, int n_in,
                              void* d_out, int out_size, void* d_ws, size_t ws_size,
                              hipStream_t stream) {
  const float* x  = (const float*)d_in[0];
  const float* Wf = (const float*)d_in[1];
  const float* Uf = (const float*)d_in[2];
  const float* bf = (const float*)d_in[3];
  const float* Wb = (const float*)d_in[4];
  const float* Ub = (const float*)d_in[5];
  const float* bb = (const float*)d_in[6];
  const float* Wd = (const float*)d_in[7];
  const float* bd = (const float*)d_in[8];
  float* out = (float*)d_out;

  char* ws = (char*)d_ws;
  ushort*   xT    = (ushort*)  (ws + 0);          // 16,777,216 B
  ushort*   UWT   = (ushort*)  (ws + 16777216);   //  4,718,592 B
  ushort*   WdTp  = (ushort*)  (ws + 21495808);   //    131,072 B
  ushort*   h_buf = (ushort*)  (ws + 21626880);   // 67,108,864 B
  unsigned* tags  = (unsigned*)(ws + 88735744);   //        128 B
  unsigned* claim = (unsigned*)(ws + 88735872);   //          8 B  (total ~88.7 MB)

  hipMemsetAsync(tags, 0, 2 * NG * sizeof(unsigned) + 2 * sizeof(unsigned), stream);
  hipLaunchKernelGGL(prep_xT,       dim3(4096), dim3(256), 0, stream, x, xT);
  hipLaunchKernelGGL(prep_UWT,      dim3(1152), dim3(256), 0, stream, Uf, Wf, Ub, Wb, UWT);
  hipLaunchKernelGGL(prep_WdT,      dim3(256),  dim3(256), 0, stream, Wd, WdTp);
  hipLaunchKernelGGL(gru_rec,       dim3(512),  dim3(384), 0, stream, xT, UWT, bf, bb, h_buf, tags, claim);
  hipLaunchKernelGGL(dense_softmax, dim3(256),  dim3(256), 0, stream, h_buf, WdTp, bd, out);
}

// Round 7
// 7094.637 us; speedup vs baseline: 1.0667x; 1.0667x over previous
//
#include <hip/hip_runtime.h>
#include <hip/hip_bf16.h>

#define F_IN  256
#define UNITS 512
#define T_SEQ 1024
#define B_SZ  32
#define NCLS  50
#define NG    16
#define NWAVE 6
#define SCOPE __HIP_MEMORY_SCOPE_AGENT

typedef short s16x8 __attribute__((ext_vector_type(8)));
typedef short s16x4 __attribute__((ext_vector_type(4)));
typedef float f32x4 __attribute__((ext_vector_type(4)));
typedef float f32x16 __attribute__((ext_vector_type(16)));

__device__ __forceinline__ ushort f2bf(float f) {
  union { float f; unsigned u; } v; v.f = f;
  unsigned r = v.u + 0x7fffu + ((v.u >> 16) & 1u);   // RNE
  return (ushort)(r >> 16);
}
__device__ __forceinline__ float bf2f(ushort u) {
  union { unsigned i; float f; } v; v.i = ((unsigned)u) << 16; return v.f;
}

// ==================== shared prep: WdT ====================
// WdT [64][1024] bf16 (rows 50..63 zero) from Wd [1024][50]
__global__ void prep_WdT(const float* __restrict__ Wd, ushort* __restrict__ WdT) {
  int idx = blockIdx.x * 256 + threadIdx.x;      // 65536
  int n = idx >> 10, k = idx & 1023;
  float v = (n < NCLS) ? Wd[(size_t)k * NCLS + n] : 0.f;
  WdT[idx] = f2bf(v);
}

// ==================== FAST PATH ====================

// UT[d][n][k<512] = U_d[k][n] ; WT[d][n][k<256] = W_d[k][n]   (bf16)
__global__ void prep_w(const float* __restrict__ Uf, const float* __restrict__ Wf,
                       const float* __restrict__ Ub, const float* __restrict__ Wb,
                       ushort* __restrict__ UT, ushort* __restrict__ WT) {
  int idx = blockIdx.x * 256 + threadIdx.x;      // [2][1536][768]
  int d = idx / (1536 * 768);
  int r = idx % (1536 * 768);
  int n = r / 768, k = r % 768;
  if (k < 512) {
    const float* U = d ? Ub : Uf;
    UT[((size_t)d * 1536 + n) * 512 + k] = f2bf(U[(size_t)k * 1536 + n]);
  } else {
    const float* W = d ? Wb : Wf;
    WT[((size_t)d * 1536 + n) * 256 + (k - 512)] = f2bf(W[(size_t)(k - 512) * 1536 + n]);
  }
}

// xg[To][lane][reg] bf16, To = ((d*2+hb)*1024 + t)*96 + tile.
// One wave computes one 16x16 C-tile: rows = batch hb*16..+16, cols = tile*16..+16
// of [z|r|h] with K=256, bias folded (b_in + b_rec for z,r; b_in only for h).
// Stored RAW in lane/reg order -> consumer adds element-wise to its own accs.
__global__ __launch_bounds__(256) void prep_xg(
    const float* __restrict__ x, const ushort* __restrict__ WT,
    const float* __restrict__ bias_f, const float* __restrict__ bias_b,
    ushort* __restrict__ xg)
{
  const int T    = blockIdx.x * 4 + (threadIdx.x >> 6);
  const int lane = threadIdx.x & 63;
  const int cl   = lane & 15;
  const int khi  = (lane >> 4) << 3;
  const int tile = T % 96;
  const int grp  = (T / 96) & 3;          // t-major dispatch for L2 reuse
  const int t    = T / 384;
  const int d = grp >> 1, hb = grp & 1;

  const int colg = tile * 16 + cl;
  const int b    = hb * 16 + cl;

  const float*  xp = x  + ((size_t)b * T_SEQ + t) * F_IN + khi;
  const ushort* wp = WT + ((size_t)d * 1536 + colg) * 256 + khi;

  f32x4 acc = {0.f, 0.f, 0.f, 0.f};
  #pragma unroll
  for (int ks = 0; ks < 8; ++ks) {
    float4 f0 = *(const float4*)(xp + ks * 32);
    float4 f1 = *(const float4*)(xp + ks * 32 + 4);
    s16x8 a;
    a[0] = (short)f2bf(f0.x); a[1] = (short)f2bf(f0.y);
    a[2] = (short)f2bf(f0.z); a[3] = (short)f2bf(f0.w);
    a[4] = (short)f2bf(f1.x); a[5] = (short)f2bf(f1.y);
    a[6] = (short)f2bf(f1.z); a[7] = (short)f2bf(f1.w);
    s16x8 w8 = *(const s16x8*)(wp + ks * 32);
    acc = __builtin_amdgcn_mfma_f32_16x16x32_bf16(a, w8, acc, 0, 0, 0);
  }
  const float* bias = d ? bias_b : bias_f;
  float bv = bias[colg] + (colg < 1024 ? bias[1536 + colg] : 0.f);
  size_t To = ((size_t)((d * 2 + hb) * 1024 + t)) * 96 + tile;
  s16x4 o;
  #pragma unroll
  for (int i = 0; i < 4; ++i) o[i] = (short)f2bf(acc[i] + bv);
  *(s16x4*)(xg + (To * 64 + lane) * 4) = o;
}

// Persistent recurrence: 4 independent WGs (d x batch-half), 1024 threads =
// 16 waves, one CU each, ZERO inter-WG communication. Wave wv owns units
// j in [wv*32, wv*32+32) across all 3 gates (6 16x16 tiles, K=512 ->
// 96 MFMA/step). h double-buffered in XOR-swizzled LDS; ONE barrier/step.
__global__ __launch_bounds__(1024, 1) void gru_rec2(
    const ushort* __restrict__ xg, const ushort* __restrict__ UT,
    const float* __restrict__ bias_f, const float* __restrict__ bias_b,
    ushort* __restrict__ h_out)
{
  const int d  = blockIdx.x >> 1;
  const int hb = blockIdx.x & 1;
  const int tid  = threadIdx.x;
  const int wv   = tid >> 6;
  const int lane = tid & 63;
  const int cl   = lane & 15;            // A-row (batch) / B-col (unit) in-tile
  const int khi  = (lane >> 4) << 3;     // k sub-offset 0,8,16,24
  const int rowbase = (lane >> 4) << 2;  // C rows 0,4,8,12

  __shared__ ushort hl[2][16 * 512];     // [buf][row*512 + swizzled unit]

  {  // zero buf 0 (h0 = 0)
    s16x8 z8 = {0, 0, 0, 0, 0, 0, 0, 0};
    *(s16x8*)(&hl[0][tid * 8]) = z8;
  }

  // --- B-fragments: U^T slice, 96 x s16x8 (384 VGPRs), static indexing ---
  s16x8 bf0[2][16], bf1[2][16], bf2[2][16];
  {
    const ushort* base = UT + ((size_t)d * 1536) * 512;
    #pragma unroll
    for (int u = 0; u < 2; ++u) {
      const ushort* p0 = base + (size_t)(0 * 512 + wv * 32 + u * 16 + cl) * 512 + khi;
      const ushort* p1 = base + (size_t)(1 * 512 + wv * 32 + u * 16 + cl) * 512 + khi;
      const ushort* p2 = base + (size_t)(2 * 512 + wv * 32 + u * 16 + cl) * 512 + khi;
      #pragma unroll
      for (int ks = 0; ks < 16; ++ks) {
        bf0[u][ks] = *(const s16x8*)(p0 + ks * 32);
        bf1[u][ks] = *(const s16x8*)(p1 + ks * 32);
        bf2[u][ks] = *(const s16x8*)(p2 + ks * 32);
      }
    }
  }

  const float* bias = d ? bias_b : bias_f;
  const float brh0 = bias[1536 + 1024 + wv * 32 + cl];
  const float brh1 = bias[1536 + 1024 + wv * 32 + 16 + cl];

  float hp0[4], hp1[4];
  #pragma unroll
  for (int i = 0; i < 4; ++i) { hp0[i] = 0.f; hp1[i] = 0.f; }

  __syncthreads();

  for (int s = 0; s < T_SEQ; ++s) {
    const int t  = d ? (T_SEQ - 1 - s) : s;
    const int pb = s & 1;          // read buffer
    const int cb = pb ^ 1;         // write buffer

    // xg loads (issued early; consumed ~2000cy later after MFMA)
    const size_t Tb = ((size_t)((d * 2 + hb) * 1024 + t)) * 96;
    const size_t lq = (size_t)lane * 4;
    s16x4 xg00 = *(const s16x4*)(xg + (Tb + 0 * 32 + wv * 2 + 0) * 256 + lq);
    s16x4 xg01 = *(const s16x4*)(xg + (Tb + 0 * 32 + wv * 2 + 1) * 256 + lq);
    s16x4 xg10 = *(const s16x4*)(xg + (Tb + 1 * 32 + wv * 2 + 0) * 256 + lq);
    s16x4 xg11 = *(const s16x4*)(xg + (Tb + 1 * 32 + wv * 2 + 1) * 256 + lq);
    s16x4 xg20 = *(const s16x4*)(xg + (Tb + 2 * 32 + wv * 2 + 0) * 256 + lq);
    s16x4 xg21 = *(const s16x4*)(xg + (Tb + 2 * 32 + wv * 2 + 1) * 256 + lq);

    f32x4 az0 = {0.f,0.f,0.f,0.f}, az1 = {0.f,0.f,0.f,0.f};
    f32x4 ar0 = {0.f,0.f,0.f,0.f}, ar1 = {0.f,0.f,0.f,0.f};
    f32x4 ah0 = {0.f,0.f,0.f,0.f}, ah1 = {0.f,0.f,0.f,0.f};

    const ushort* hbase = &hl[pb][cl * 512];
    const int swz = (cl & 7) << 3;
    #pragma unroll
    for (int ks = 0; ks < 16; ++ks) {
      s16x8 a = *(const s16x8*)(hbase + (((ks * 32) + khi) ^ swz));
      az0 = __builtin_amdgcn_mfma_f32_16x16x32_bf16(a, bf0[0][ks], az0, 0, 0, 0);
      az1 = __builtin_amdgcn_mfma_f32_16x16x32_bf16(a, bf0[1][ks], az1, 0, 0, 0);
      ar0 = __builtin_amdgcn_mfma_f32_16x16x32_bf16(a, bf1[0][ks], ar0, 0, 0, 0);
      ar1 = __builtin_amdgcn_mfma_f32_16x16x32_bf16(a, bf1[1][ks], ar1, 0, 0, 0);
      ah0 = __builtin_amdgcn_mfma_f32_16x16x32_bf16(a, bf2[0][ks], ah0, 0, 0, 0);
      ah1 = __builtin_amdgcn_mfma_f32_16x16x32_bf16(a, bf2[1][ks], ah1, 0, 0, 0);
    }

    // gate math fully in-register; exp2-safe forms, no clamps needed
    ushort* hw = &hl[cb][0];
    ushort* ho = h_out + ((size_t)(d * T_SEQ + t) * B_SZ + hb * 16) * UNITS;
    #pragma unroll
    for (int i = 0; i < 4; ++i) {
      const int row = rowbase + i;
      const int rswz = (row & 7) << 3;
      // u = 0
      {
        float xz = bf2f((ushort)xg00[i]);
        float xr = bf2f((ushort)xg10[i]);
        float xh = bf2f((ushort)xg20[i]);
        float z  = __builtin_amdgcn_rcpf(1.f + __expf(-(az0[i] + xz)));
        float r  = __builtin_amdgcn_rcpf(1.f + __expf(-(ar0[i] + xr)));
        float th = xh + r * (ah0[i] + brh0);
        float hh = 1.f - 2.f * __builtin_amdgcn_rcpf(1.f + __expf(2.f * th));
        float hn = z * hp0[i] + (1.f - z) * hh;
        hp0[i] = hn;
        ushort hv = f2bf(hn);
        int j = wv * 32 + cl;
        hw[row * 512 + (j ^ rswz)] = hv;
        ho[(size_t)row * UNITS + j] = hv;
      }
      // u = 1
      {
        float xz = bf2f((ushort)xg01[i]);
        float xr = bf2f((ushort)xg11[i]);
        float xh = bf2f((ushort)xg21[i]);
        float z  = __builtin_amdgcn_rcpf(1.f + __expf(-(az1[i] + xz)));
        float r  = __builtin_amdgcn_rcpf(1.f + __expf(-(ar1[i] + xr)));
        float th = xh + r * (ah1[i] + brh1);
        float hh = 1.f - 2.f * __builtin_amdgcn_rcpf(1.f + __expf(2.f * th));
        float hn = z * hp1[i] + (1.f - z) * hh;
        hp1[i] = hn;
        ushort hv = f2bf(hn);
        int j = wv * 32 + 16 + cl;
        hw[row * 512 + (j ^ rswz)] = hv;
        ho[(size_t)row * UNITS + j] = hv;
      }
    }
    __syncthreads();   // writes(cb) complete before next step reads them
  }
}

// ==================== FALLBACK PATH (R5, proven) ====================

__global__ void prep_xT(const float* __restrict__ x, ushort* __restrict__ xT) {
  int idx = blockIdx.x * 256 + threadIdx.x;
  int b = idx >> 15; int r = idx & 32767; int t = r >> 5; int c = r & 31;
  const float4* s4 = (const float4*)(x + ((size_t)b * T_SEQ + t) * F_IN + c * 8);
  float4 f0 = s4[0], f1 = s4[1];
  s16x8 o;
  o[0] = (short)f2bf(f0.x); o[1] = (short)f2bf(f0.y);
  o[2] = (short)f2bf(f0.z); o[3] = (short)f2bf(f0.w);
  o[4] = (short)f2bf(f1.x); o[5] = (short)f2bf(f1.y);
  o[6] = (short)f2bf(f1.z); o[7] = (short)f2bf(f1.w);
  *(s16x8*)(xT + ((size_t)t * B_SZ + b) * F_IN + c * 8) = o;
}

__global__ void prep_UWT(const float* __restrict__ Uf, const float* __restrict__ Wf,
                         const float* __restrict__ Ub, const float* __restrict__ Wb,
                         ushort* __restrict__ UWT) {
  int idx = blockIdx.x * 256 + threadIdx.x;
  int d = idx / 147456; int r = idx % 147456; int n = r / 96; int ck = r % 96;
  const float* U = d ? Ub : Uf;
  const float* W = d ? Wb : Wf;
  s16x8 o;
  #pragma unroll
  for (int i = 0; i < 8; ++i) {
    int k = ck * 8 + i;
    float v = (k < UNITS) ? U[(size_t)k * 1536 + n] : W[(size_t)(k - UNITS) * 1536 + n];
    o[i] = (short)f2bf(v);
  }
  *(s16x8*)(UWT + ((size_t)d * 1536 + n) * 768 + ck * 8) = o;
}

__global__ __launch_bounds__(384, 2) void gru_rec_fb(
    const ushort* __restrict__ xT, const ushort* __restrict__ UWT,
    const float* __restrict__ bias_f, const float* __restrict__ bias_b,
    ushort* __restrict__ h_out, unsigned* __restrict__ tags)
{
  const int g  = blockIdx.x;
  const int d  = g >> 4;
  const int gg = g & 15;
  const int tid  = threadIdx.x;
  const int wv   = tid >> 6;
  const int lane = tid & 63;
  const int col  = lane & 31;
  const int half = lane >> 5;
  const int gate = wv >> 1;
  const int kh   = wv & 1;

  __shared__ float slot[2][32][128];

  s16x8 bfrag[24];
  {
    const ushort* bp = UWT + ((size_t)d * 1536 + gate * UNITS + gg * 32 + col) * 768
                       + kh * 384 + half * 8;
    #pragma unroll
    for (int c = 0; c < 24; ++c) bfrag[c] = *(const s16x8*)(bp + c * 16);
  }

  const float* bias = d ? bias_b : bias_f;
  float bz[3], br[3], bih[3], brh[3], hprev[3];
  #pragma unroll
  for (int i = 0; i < 3; ++i) {
    int e = tid + 384 * i;
    int j = gg * 32 + (e & 31);
    bz[i] = br[i] = bih[i] = brh[i] = 0.f;
    hprev[i] = 0.f;
    if (e < 1024) {
      bz[i]  = bias[j]        + bias[1536 + j];
      br[i]  = bias[512 + j]  + bias[1536 + 512 + j];
      bih[i] = bias[1024 + j];
      brh[i] = bias[1536 + 1024 + j];
    }
  }

  for (int s = 0; s < T_SEQ; ++s) {
    const int t_in = d ? (T_SEQ - 1 - s) : s;
    f32x16 acc_a, acc_b;
    #pragma unroll
    for (int i = 0; i < 16; ++i) { acc_a[i] = 0.f; acc_b[i] = 0.f; }

    if (kh) {
      const ushort* xp = xT + ((size_t)t_in * B_SZ + col) * F_IN + half * 8;
      #pragma unroll
      for (int grp = 0; grp < 2; ++grp) {
        s16x8 a[8];
        #pragma unroll
        for (int i = 0; i < 8; ++i) a[i] = *(const s16x8*)(xp + (grp * 8 + i) * 16);
        #pragma unroll
        for (int i = 0; i < 8; ++i)
          acc_b = __builtin_amdgcn_mfma_f32_32x32x16_bf16(a[i], bfrag[8 + grp * 8 + i], acc_b, 0, 0, 0);
      }
    }

    if (s > 0) {
      if (wv == 0) {
        const unsigned expv = (unsigned)s;
        const unsigned* tg = tags + d * NG;
        bool done;
        do {
          unsigned v = (lane < NG)
              ? __hip_atomic_load(tg + lane, __ATOMIC_RELAXED, SCOPE) : expv;
          done = __all(v >= expv);
          if (!done) __builtin_amdgcn_s_sleep(1);
        } while (!done);
      }
      __syncthreads();

      const int t_prev = d ? (T_SEQ - s) : (s - 1);
      const ushort* ap = h_out + ((size_t)(d * T_SEQ + t_prev) * B_SZ + col) * UNITS
                         + kh * 384 + half * 8;
      if (kh) {
        s16x8 a[8];
        #pragma unroll
        for (int i = 0; i < 8; ++i) a[i] = *(const s16x8*)(ap + i * 16);
        #pragma unroll
        for (int i = 0; i < 8; ++i)
          acc_a = __builtin_amdgcn_mfma_f32_32x32x16_bf16(a[i], bfrag[i], acc_a, 0, 0, 0);
      } else {
        #pragma unroll
        for (int grp = 0; grp < 2; ++grp) {
          s16x8 a[12];
          #pragma unroll
          for (int i = 0; i < 12; ++i) a[i] = *(const s16x8*)(ap + (grp * 12 + i) * 16);
          #pragma unroll
          for (int i = 0; i < 12; ++i)
            acc_a = __builtin_amdgcn_mfma_f32_32x32x16_bf16(a[i], bfrag[grp * 12 + i], acc_a, 0, 0, 0);
        }
      }
    }

    #pragma unroll
    for (int i = 0; i < 16; ++i) {
      int brow = (i & 3) + 8 * (i >> 2) + 4 * half;
      if (gate < 2) {
        slot[kh][brow][gate * 32 + col] = acc_a[i] + acc_b[i];
      } else {
        slot[kh][brow][64 + col] = acc_a[i];
        if (kh) slot[1][brow][96 + col] = acc_b[i];
      }
    }
    __syncthreads();

    #pragma unroll
    for (int i = 0; i < 3; ++i) {
      int e = tid + 384 * i;
      if (e < 1024) {
        int b = e >> 5, j = e & 31;
        float rz = slot[0][b][j]      + slot[1][b][j]      + bz[i];
        float rr = slot[0][b][32 + j] + slot[1][b][32 + j] + br[i];
        float rh = slot[0][b][64 + j] + slot[1][b][64 + j] + brh[i];
        float xh = slot[1][b][96 + j] + bih[i];
        rz = fminf(fmaxf(rz, -30.f), 30.f);
        rr = fminf(fmaxf(rr, -30.f), 30.f);
        float z  = 1.f / (1.f + __expf(-rz));
        float rg = 1.f / (1.f + __expf(-rr));
        float ti = xh + rg * rh;
        ti = fminf(fmaxf(ti, -15.f), 15.f);
        float ex = __expf(2.f * ti);
        float hh = (ex - 1.f) / (ex + 1.f);
        float hn = z * hprev[i] + (1.f - z) * hh;
        hprev[i] = hn;
        __hip_atomic_store(
            h_out + ((size_t)(d * T_SEQ + t_in) * B_SZ + b) * UNITS + gg * 32 + j,
            (ushort)f2bf(hn), __ATOMIC_RELAXED, SCOPE);
      }
    }
    __syncthreads();
    if (tid == 0)
      __hip_atomic_store(tags + d * NG + gg, (unsigned)(s + 1),
                         __ATOMIC_RELAXED, SCOPE);
  }
}

// ==================== dense + softmax (shared) ====================
__global__ __launch_bounds__(256) void dense_softmax(
    const ushort* __restrict__ h_out, const ushort* __restrict__ WdT,
    const float* __restrict__ bd, float* __restrict__ out)
{
  const int tid  = threadIdx.x;
  const int w    = tid >> 6, lane = tid & 63;
  const int col  = lane & 31, half = lane >> 5;
  const int t = blockIdx.x * 4 + w;

  __shared__ float lds[4][32][66];

  f32x16 acc0, acc1;
  #pragma unroll
  for (int i = 0; i < 16; ++i) { acc0[i] = 0.f; acc1[i] = 0.f; }

  const ushort* af  = h_out + ((size_t)t * B_SZ + col) * UNITS + half * 8;
  const ushort* ab  = h_out + ((size_t)(T_SEQ + t) * B_SZ + col) * UNITS + half * 8;
  const ushort* bp0 = WdT + (size_t)col * 1024 + half * 8;
  const ushort* bp1 = WdT + (size_t)(col + 32) * 1024 + half * 8;

  #pragma unroll 4
  for (int ks = 0; ks < 64; ++ks) {
    s16x8 a  = (ks < 32) ? *(const s16x8*)(af + ks * 16)
                         : *(const s16x8*)(ab + (ks - 32) * 16);
    s16x8 b0 = *(const s16x8*)(bp0 + ks * 16);
    s16x8 b1 = *(const s16x8*)(bp1 + ks * 16);
    acc0 = __builtin_amdgcn_mfma_f32_32x32x16_bf16(a, b0, acc0, 0, 0, 0);
    acc1 = __builtin_amdgcn_mfma_f32_32x32x16_bf16(a, b1, acc1, 0, 0, 0);
  }

  #pragma unroll
  for (int i = 0; i < 16; ++i) {
    int b = (i & 3) + 8 * (i >> 2) + 4 * half;
    lds[w][b][col]      = acc0[i];
    lds[w][b][32 + col] = acc1[i];
  }
  __syncthreads();

  if (tid < 128) {
    int tl = tid >> 5, b = tid & 31;
    int tt = blockIdx.x * 4 + tl;
    float v[NCLS];
    float m = -1e30f;
    #pragma unroll
    for (int c = 0; c < NCLS; ++c) { v[c] = lds[tl][b][c] + bd[c]; m = fmaxf(m, v[c]); }
    float sum = 0.f;
    #pragma unroll
    for (int c = 0; c < NCLS; ++c) { float e = __expf(v[c] - m); v[c] = e; sum += e; }
    float inv = 1.f / sum;
    float* op = out + ((size_t)b * T_SEQ + tt) * NCLS;
    #pragma unroll
    for (int c = 0; c < NCLS; ++c) op[c] = v[c] * inv;
  }
}

// ==================== launch ====================
extern "C" void kernel_launch(void* const* d_in, const int* in_sizes, int n_in,
                              void* d_out, int out_size, void* d_ws, size_t ws_size,
                              hipStream_t stream) {
  const float* x  = (const float*)d_in[0];
  const float* Wf = (const float*)d_in[1];
  const float* Uf = (const float*)d_in[2];
  const float* bf = (const float*)d_in[3];
  const float* Wb = (const float*)d_in[4];
  const float* Ub = (const float*)d_in[5];
  const float* bb = (const float*)d_in[6];
  const float* Wd = (const float*)d_in[7];
  const float* bd = (const float*)d_in[8];
  float* out = (float*)d_out;
  char* ws = (char*)d_ws;

  if (ws_size >= 273285120ULL) {
    // ---- fast path ----
    ushort* UT    = (ushort*)(ws + 0);           //   3,145,728 B
    ushort* WT    = (ushort*)(ws + 3145728);     //   1,572,864 B
    ushort* WdTp  = (ushort*)(ws + 4718592);     //     131,072 B
    ushort* h_buf = (ushort*)(ws + 4849664);     //  67,108,864 B
    ushort* xg    = (ushort*)(ws + 71958528);    // 201,326,592 B -> 273,285,120

    hipLaunchKernelGGL(prep_w,        dim3(9216),  dim3(256),  0, stream, Uf, Wf, Ub, Wb, UT, WT);
    hipLaunchKernelGGL(prep_WdT,      dim3(256),   dim3(256),  0, stream, Wd, WdTp);
    hipLaunchKernelGGL(prep_xg,       dim3(98304), dim3(256),  0, stream, x, WT, bf, bb, xg);
    hipLaunchKernelGGL(gru_rec2,      dim3(4),     dim3(1024), 0, stream, xg, UT, bf, bb, h_buf);
    hipLaunchKernelGGL(dense_softmax, dim3(256),   dim3(256),  0, stream, h_buf, WdTp, bd, out);
  } else {
    // ---- fallback: proven R5 pipeline ----
    ushort*   xT    = (ushort*)  (ws + 0);
    ushort*   UWT   = (ushort*)  (ws + 16777216);
    ushort*   WdTp  = (ushort*)  (ws + 21495808);
    ushort*   h_buf = (ushort*)  (ws + 21626880);
    unsigned* tags  = (unsigned*)(ws + 88735744);

    hipMemsetAsync(tags, 0, 2 * NG * sizeof(unsigned), stream);
    hipLaunchKernelGGL(prep_xT,       dim3(4096), dim3(256), 0, stream, x, xT);
    hipLaunchKernelGGL(prep_UWT,      dim3(1152), dim3(256), 0, stream, Uf, Wf, Ub, Wb, UWT);
    hipLaunchKernelGGL(prep_WdT,      dim3(256),  dim3(256), 0, stream, Wd, WdTp);
    hipLaunchKernelGGL(gru_rec_fb,    dim3(32),   dim3(384), 0, stream, xT, UWT, bf, bb, h_buf, tags);
    hipLaunchKernelGGL(dense_softmax, dim3(256),  dim3(256), 0, stream, h_buf, WdTp, bd, out);
  }
}